// Round 5
// baseline (2029.042 us; speedup 1.0000x reference)
//
#include <hip/hip_runtime.h>
#include <stdint.h>

#define Hn 512
#define Dn 128
#define Nn 64
#define Tn 512
#define NT (Nn*Tn)   // 32768

typedef unsigned int uint;
typedef unsigned short ushort;
typedef unsigned long long u64;

typedef __attribute__((ext_vector_type(4))) float f32x4;

#define POISON 0xFFFFFFFFFFFFFFFFULL  // u64 of fp8 data bytes (<=0x7F each) can never be this

// ---------- ws layout (bytes) ----------
// emitb : 0x0000000  NT*Hn*2  = 32 MB   (exp(emit-rowmax), bf16)
// rm    : 0x2000000  NT*4     = 128 KB
// wmat  : 0x2020000  Hn*Dn*4  = 256 KB
// bias  : 0x2060000  Hn*4     = 2 KB
// cs    : 0x2061000  Hn*4     (448/colmax of P)
// rcsg  : 0x2062000  Hn*4     (colmax/448)
// pq    : 0x2070000  2*16*16*64*8 = 256 KB (P fp8 e4m3, MFMA B-frag order [half][ktg][ntl][lane])
// mb    : 0x20B0000  16 boxes * 520 u64 (alpha mailboxes [pair][producer-half][grp2][parity])

__device__ inline float bf2f(ushort u) { union { uint i; float f; } v; v.i = uint(u) << 16; return v.f; }
__device__ inline ushort f2bf(float f) {
  union { uint i; float f; } v; v.f = f;
  uint u = v.i;
  uint r = (u + 0x7FFFu + ((u >> 16) & 1u)) >> 16;
  return ushort(r);
}
__device__ inline u64 a64(const u64* p) {
  return __hip_atomic_load(p, __ATOMIC_RELAXED, __HIP_MEMORY_SCOPE_AGENT);
}
__device__ inline void s64(u64* p, u64 v) {
  __hip_atomic_store(p, v, __ATOMIC_RELAXED, __HIP_MEMORY_SCOPE_AGENT);
}
// e4m3fn decode (non-negative only); finale only
__device__ inline float fp8val(uint b) {
  uint e = (b >> 3) & 15u, m = b & 7u;
  return e ? ldexpf((float)(8u + m), (int)e - 10) : ldexpf((float)m, -9);
}
// pack 8 floats (k-ascending) to 8 e4m3 bytes; SAME helper packs A and B frags,
// so any HW k-permutation within the 32-k tile cancels between operands.
__device__ inline u64 pack8fp8(const float* v, float qs) {
  int lo = 0, hi = 0;
  lo = __builtin_amdgcn_cvt_pk_fp8_f32(v[0] * qs, v[1] * qs, lo, false);
  lo = __builtin_amdgcn_cvt_pk_fp8_f32(v[2] * qs, v[3] * qs, lo, true);
  hi = __builtin_amdgcn_cvt_pk_fp8_f32(v[4] * qs, v[5] * qs, hi, false);
  hi = __builtin_amdgcn_cvt_pk_fp8_f32(v[6] * qs, v[7] * qs, hi, true);
  return (u64)(uint)lo | ((u64)(uint)hi << 32);
}

__global__ void k_zero(u64* mb) {
  int i = blockIdx.x * 256 + threadIdx.x;
  if (i < 16 * 520) mb[i] = POISON;
}

__global__ void k_prep(const float* __restrict__ py, float* __restrict__ wmat, float* __restrict__ bias) {
  int h = blockIdx.x, d = threadIdx.x;
  float p = py[h * Dn + d];
  float lp = logf(p), l1 = log1pf(-p);
  wmat[h * Dn + d] = lp - l1;
  float v = l1;
  for (int o = 1; o < 64; o <<= 1) v += __shfl_xor(v, o, 64);
  __shared__ float s2[2];
  if ((threadIdx.x & 63) == 0) s2[threadIdx.x >> 6] = v;
  __syncthreads();
  if (threadIdx.x == 0) bias[h] = s2[0] + s2[1];
}

__global__ void k_cs(const float* __restrict__ px, float* __restrict__ cs, float* __restrict__ rcsg) {
  int j = threadIdx.x;
  float m = 0.f;
#pragma unroll 8
  for (int k = 0; k < Hn; k++) m = fmaxf(m, px[(size_t)k * Hn + j]);
  cs[j] = 448.0f / m;
  rcsg[j] = m * (1.0f / 448.0f);
}

__global__ __launch_bounds__(256) void k_pq(const float* __restrict__ px, const float* __restrict__ cs,
                                            u64* __restrict__ pq) {
  __shared__ float ksl[32][260];
  int g = blockIdx.x & 1, kt = blockIdx.x >> 1;
  int t = threadIdx.x;
  int k0 = kt * 32;
  for (int i = 0; i < 8; i++) {
    int q = i * 256 + t;
    int row = q >> 6, c4 = q & 63;
    float4 v = *(const float4*)(px + (size_t)(k0 + row) * Hn + g * 256 + c4 * 4);
    ksl[row][c4 * 4 + 0] = v.x; ksl[row][c4 * 4 + 1] = v.y;
    ksl[row][c4 * 4 + 2] = v.z; ksl[row][c4 * 4 + 3] = v.w;
  }
  __syncthreads();
  for (int i = 0; i < 4; i++) {
    int fid = i * 256 + t;
    int ntl = fid >> 6, l = fid & 63;
    int col = ntl * 16 + (l & 15);
    int kr0 = (l >> 4) * 8;
    float csv = cs[g * 256 + col];
    float vv[8];
#pragma unroll
    for (int j = 0; j < 8; j++) vv[j] = ksl[kr0 + j][col];
    pq[(size_t)(((g * 16 + kt) * 16 + ntl) * 64 + l)] = pack8fp8(vv, csv);
  }
}

__global__ __launch_bounds__(256) void k_emit(const float* __restrict__ A, const float* __restrict__ wmat,
                                              const float* __restrict__ bias, ushort* __restrict__ eb) {
  __shared__ float As[Dn][64];
  __shared__ float Bs[Dn][64];
  int t = threadIdx.x;
  int r0 = blockIdx.y * 64, h0 = blockIdx.x * 64;
  int row = t >> 2, q = t & 3;
  for (int i = 0; i < 8; i++) {
    int ch = q + i * 4;
    float4 a = *(const float4*)(A + (size_t)(r0 + row) * Dn + ch * 4);
    As[ch * 4 + 0][row] = a.x; As[ch * 4 + 1][row] = a.y;
    As[ch * 4 + 2][row] = a.z; As[ch * 4 + 3][row] = a.w;
    float4 b = *(const float4*)(wmat + (size_t)(h0 + row) * Dn + ch * 4);
    Bs[ch * 4 + 0][row] = b.x; Bs[ch * 4 + 1][row] = b.y;
    Bs[ch * 4 + 2][row] = b.z; Bs[ch * 4 + 3][row] = b.w;
  }
  __syncthreads();
  int tx = t & 15, ty = t >> 4;
  float acc[4][4] = {};
  for (int k = 0; k < Dn; k++) {
    float av[4], bv[4];
    *(float4*)av = *(const float4*)&As[k][ty * 4];
    *(float4*)bv = *(const float4*)&Bs[k][tx * 4];
#pragma unroll
    for (int ii = 0; ii < 4; ii++)
#pragma unroll
      for (int jj = 0; jj < 4; jj++) acc[ii][jj] += av[ii] * bv[jj];
  }
  float bsv[4];
  *(float4*)bsv = *(const float4*)(bias + h0 + tx * 4);
#pragma unroll
  for (int ii = 0; ii < 4; ii++) {
    int r = r0 + ty * 4 + ii;
    ushort4 u;
    u.x = f2bf(acc[ii][0] + bsv[0]); u.y = f2bf(acc[ii][1] + bsv[1]);
    u.z = f2bf(acc[ii][2] + bsv[2]); u.w = f2bf(acc[ii][3] + bsv[3]);
    *(ushort4*)(eb + (size_t)r * Hn + h0 + tx * 4) = u;
  }
}

__global__ void k_rowmax(const ushort* __restrict__ eb, float* __restrict__ rm) {
  int r = blockIdx.x, lane = threadIdx.x;
  uint4 u = *(const uint4*)(eb + (size_t)r * Hn + lane * 8);
  float m = bf2f(ushort(u.x & 0xffff));
  m = fmaxf(m, bf2f(ushort(u.x >> 16)));
  m = fmaxf(m, bf2f(ushort(u.y & 0xffff))); m = fmaxf(m, bf2f(ushort(u.y >> 16)));
  m = fmaxf(m, bf2f(ushort(u.z & 0xffff))); m = fmaxf(m, bf2f(ushort(u.z >> 16)));
  m = fmaxf(m, bf2f(ushort(u.w & 0xffff))); m = fmaxf(m, bf2f(ushort(u.w >> 16)));
  for (int o = 1; o < 64; o <<= 1) m = fmaxf(m, __shfl_xor(m, o, 64));
  if (lane == 0) rm[r] = m;
}

__global__ void k_bexp(ushort* __restrict__ eb, const float* __restrict__ rm) {
  int i = blockIdx.x * 256 + threadIdx.x;
  uint* p = (uint*)eb;
  uint u = p[i];
  float m = rm[i >> 8];
  float f0 = expf(bf2f(ushort(u & 0xffff)) - m);
  float f1 = expf(bf2f(ushort(u >> 16)) - m);
  p[i] = uint(f2bf(f0)) | (uint(f2bf(f1)) << 16);
}

// 4 WGs = 2 pairs x 2 col-halves; each pair interleaves TWO seq-groups so the
// cross-XCD exchange latency of one group hides under the other's compute.
// P fp8 B-frags live in 64 VGPRs/lane (compile-time indexed). 512 threads.
__global__ __launch_bounds__(512) void k_rec3(
    const ushort* __restrict__ eb, const float* __restrict__ rm,
    const u64* __restrict__ pq, const float* __restrict__ px,
    const float* __restrict__ rcsg, const int* __restrict__ lens,
    u64* __restrict__ mb, float* __restrict__ outp) {
  const int pp = blockIdx.x >> 1;   // pair 0..1 (seqs pp*32..pp*32+31)
  const int hh = blockIdx.x & 1;    // column half
  const int t = threadIdx.x;        // 0..511
  const int w = t >> 6, lane = t & 63, quad = (t >> 4) & 3, l15 = t & 15;
  const int n0 = w * 2, n1 = n0 + 1;

  __shared__ float ut[16][260];      // per-phase fp32 staging (reused by both groups)
  __shared__ u64 Aq[2][2][512];      // [grp][k-side][kr*64+lane] fp8 A-frags
  __shared__ float rcsL[256];
  __shared__ float moS[2][16], mpS[2][16], rqsS[2][16], CaccS[2][16];
  __shared__ float sred0[8][16], sred1[8][16];
  __shared__ int lenl[2][16];

  // ---- P B-frags into registers: own/peer k-half x 2 ntl, 8 k-tiles each ----
  u64 BO0[8], BO1[8], BP0[8], BP1[8];
#pragma unroll
  for (int kr = 0; kr < 8; kr++) {
    int kto = hh * 8 + kr, ktp = (1 - hh) * 8 + kr;
    BO0[kr] = pq[(size_t)(((hh * 16 + kto) * 16 + n0) * 64 + lane)];
    BO1[kr] = pq[(size_t)(((hh * 16 + kto) * 16 + n1) * 64 + lane)];
    BP0[kr] = pq[(size_t)(((hh * 16 + ktp) * 16 + n0) * 64 + lane)];
    BP1[kr] = pq[(size_t)(((hh * 16 + ktp) * 16 + n1) * 64 + lane)];
  }
  if (t < 256) rcsL[t] = rcsg[hh * 256 + t];
  if (t < 32) {
    int g = t >> 4, s = t & 15;
    lenl[g][s] = lens[(pp * 2 + g) * 16 + s];
    if (hh == 0) CaccS[g][s] = rm[(size_t)((pp * 2 + g) * 16 + s) * Tn];
  }
  const int gcb = hh * 256;
  __syncthreads();
  const int te0 = lenl[0][15], te1 = lenl[1][15];

  // ---- init both groups (t = 0) ----
#pragma unroll
  for (int g = 0; g < 2; g++) {
    int gg = pp * 2 + g;
    {
      int s = t >> 5, c8 = (t & 31) * 8;
      float4 p0 = *(const float4*)(px + gcb + c8);
      float4 p1 = *(const float4*)(px + gcb + c8 + 4);
      const ushort* ep = eb + ((size_t)(gg * 16 + s) * Tn) * Hn + gcb + c8;
      ut[s][c8 + 0] = p0.x * bf2f(ep[0]); ut[s][c8 + 1] = p0.y * bf2f(ep[1]);
      ut[s][c8 + 2] = p0.z * bf2f(ep[2]); ut[s][c8 + 3] = p0.w * bf2f(ep[3]);
      ut[s][c8 + 4] = p1.x * bf2f(ep[4]); ut[s][c8 + 5] = p1.y * bf2f(ep[5]);
      ut[s][c8 + 6] = p1.z * bf2f(ep[6]); ut[s][c8 + 7] = p1.w * bf2f(ep[7]);
    }
    __syncthreads();
    {
      int s = t >> 5, ch = t & 31;
      float4 x = *(float4*)&ut[s][ch * 8];
      float4 y = *(float4*)&ut[s][ch * 8 + 4];
      float m = fmaxf(fmaxf(fmaxf(x.x, x.y), fmaxf(x.z, x.w)),
                      fmaxf(fmaxf(y.x, y.y), fmaxf(y.z, y.w)));
      for (int o = 1; o <= 16; o <<= 1) m = fmaxf(m, __shfl_xor(m, o, 64));
      if (ch == 0) { rqsS[g][s] = 448.0f * __builtin_amdgcn_rcpf(m); moS[g][s] = m * (1.0f / 448.0f); }
    }
    __syncthreads();
    {
      int s = l15, k0 = w * 32 + quad * 8;
      float vv[8];
#pragma unroll
      for (int j = 0; j < 8; j++) vv[j] = ut[s][k0 + j];
      u64 nv = pack8fp8(vv, rqsS[g][s]);
      Aq[g][hh][t] = nv;
      u64* ob = mb + (size_t)(((pp * 2 + hh) * 2 + g) * 2 + 0) * 520;
      asm volatile("s_waitcnt vmcnt(0)" ::: "memory");
      s64(ob + t, nv);
      if (t < 8) {
        u64 sv = (u64)__float_as_uint(moS[g][2 * t]) | ((u64)__float_as_uint(moS[g][2 * t + 1]) << 32);
        s64(ob + 512 + t, sv);
      }
    }
    __syncthreads();
  }

  // ---- early probes + prefetch for ts=1 ----
  u64 pvE[2], pv2E[2];
  int armstep[2];
  ushort bq0[2][4], bq1[2][4];
  float rmpre[2];
#pragma unroll
  for (int g = 0; g < 2; g++) {
    u64* nb = mb + (size_t)(((pp * 2 + (1 - hh)) * 2 + g) * 2 + 0) * 520;
    pvE[g] = a64(nb + t);
    pv2E[g] = (t < 8) ? a64(nb + 512 + t) : 0;
    armstep[g] = 1;
#pragma unroll
    for (int r = 0; r < 4; r++) {
      int s = quad * 4 + r;
      const ushort* ebp = eb + ((size_t)((pp * 2 + g) * 16 + s) * Tn + 1) * Hn + gcb;
      bq0[g][r] = ebp[n0 * 16 + l15];
      bq1[g][r] = ebp[n1 * 16 + l15];
    }
    if (hh == 0 && t < 16) rmpre[g] = rm[(size_t)((pp * 2 + g) * 16 + t) * Tn + 1];
  }

  const int tmax = te0 > te1 ? te0 : te1;
  for (int ts = 1; ts < tmax; ts++) {
#pragma unroll
    for (int g = 0; g < 2; g++) {
      const int teg = g == 0 ? te0 : te1;
      if (ts < teg) {
        const int pr = (ts + 1) & 1;
        u64* inb = mb + (size_t)(((pp * 2 + (1 - hh)) * 2 + g) * 2 + pr) * 520;
        u64 pv = (armstep[g] == ts) ? pvE[g] : POISON;
        u64 pv2 = (armstep[g] == ts) ? pv2E[g] : POISON;
        // own-k-half MFMAs while the probe is in flight
        f32x4 ao0 = {0.f, 0.f, 0.f, 0.f}, ao1 = {0.f, 0.f, 0.f, 0.f};
#pragma unroll
        for (int kr = 0; kr < 8; kr++) {
          u64 af = Aq[g][hh][kr * 64 + lane];
          ao0 = __builtin_amdgcn_mfma_f32_16x16x32_fp8_fp8((long)af, (long)BO0[kr], ao0, 0, 0, 0);
          ao1 = __builtin_amdgcn_mfma_f32_16x16x32_fp8_fp8((long)af, (long)BO1[kr], ao1, 0, 0, 0);
        }
        // detect + stage peer frags + re-poison
        while (pv == POISON) pv = a64(inb + t);
        Aq[g][1 - hh][t] = pv;
        s64(inb + t, POISON);
        if (t < 8) {
          while (pv2 == POISON) pv2 = a64(inb + 512 + t);
          mpS[g][2 * t] = __uint_as_float((uint)pv2);
          mpS[g][2 * t + 1] = __uint_as_float((uint)(pv2 >> 32));
          s64(inb + 512 + t, POISON);
        }
        __syncthreads();  // B1
        // peer-k-half MFMAs
        f32x4 ap0 = {0.f, 0.f, 0.f, 0.f}, ap1 = {0.f, 0.f, 0.f, 0.f};
#pragma unroll
        for (int kr = 0; kr < 8; kr++) {
          u64 af = Aq[g][1 - hh][kr * 64 + lane];
          ap0 = __builtin_amdgcn_mfma_f32_16x16x32_fp8_fp8((long)af, (long)BP0[kr], ap0, 0, 0, 0);
          ap1 = __builtin_amdgcn_mfma_f32_16x16x32_fp8_fp8((long)af, (long)BP1[kr], ap1, 0, 0, 0);
        }
        // off-path Cacc (hh==0): OLD moS + fresh mpS
        if (hh == 0 && t < 16 && ts < lenl[g][t])
          CaccS[g][t] += logf(fmaxf(moS[g][t], mpS[g][t])) + rmpre[g];
        // epilogue
        {
          int j0 = n0 * 16 + l15, j1 = j0 + 16;
          float rc0 = rcsL[j0], rc1 = rcsL[j1];
#pragma unroll
          for (int r = 0; r < 4; r++) {
            int s = quad * 4 + r;
            float mo_ = moS[g][s], mp_ = mpS[g][s];
            float rg = __builtin_amdgcn_rcpf(fmaxf(mo_, mp_));
            ut[s][j0] = (mo_ * ao0[r] + mp_ * ap0[r]) * rg * bf2f(bq0[g][r]) * rc0;
            ut[s][j1] = (mo_ * ao1[r] + mp_ * ap1[r]) * rg * bf2f(bq1[g][r]) * rc1;
          }
        }
        __syncthreads();  // B2
        // new local max + scale update (frozen seqs keep old scale)
        {
          int s = t >> 5, ch = t & 31;
          float4 x = *(float4*)&ut[s][ch * 8];
          float4 y = *(float4*)&ut[s][ch * 8 + 4];
          float m = fmaxf(fmaxf(fmaxf(x.x, x.y), fmaxf(x.z, x.w)),
                          fmaxf(fmaxf(y.x, y.y), fmaxf(y.z, y.w)));
          for (int o = 1; o <= 16; o <<= 1) m = fmaxf(m, __shfl_xor(m, o, 64));
          if (ch == 0) {
            rqsS[g][s] = 448.0f * __builtin_amdgcn_rcpf(m);
            if (ts < lenl[g][s]) moS[g][s] = m * (1.0f / 448.0f);
          }
        }
        __syncthreads();  // B3
        // quantize / resend-frozen; ship
        {
          int s = l15, k0 = w * 32 + quad * 8;
          u64 old = Aq[g][hh][t];
          u64 nv;
          if (ts < lenl[g][s]) {
            float vv[8];
#pragma unroll
            for (int j = 0; j < 8; j++) vv[j] = ut[s][k0 + j];
            nv = pack8fp8(vv, rqsS[g][s]);
          } else {
            nv = old;
          }
          Aq[g][hh][t] = nv;
          u64* ob = mb + (size_t)(((pp * 2 + hh) * 2 + g) * 2 + (ts & 1)) * 520;
          asm volatile("s_waitcnt vmcnt(0)" ::: "memory");  // poisons land before new data
          s64(ob + t, nv);
          if (t < 8) {
            u64 sv = (u64)__float_as_uint(moS[g][2 * t]) | ((u64)__float_as_uint(moS[g][2 * t + 1]) << 32);
            s64(ob + 512 + t, sv);
          }
        }
        // arm next phase's probe (group g^1) with step-exact tag
        {
          int go = g ^ 1;
          int tq = (g == 0) ? ts : ts + 1;
          int ap_ = (tq + 1) & 1;   // = (tq-1)&1, box consumed at step tq
          u64* nb = mb + (size_t)(((pp * 2 + (1 - hh)) * 2 + go) * 2 + ap_) * 520;
          pvE[go] = a64(nb + t);
          pv2E[go] = (t < 8) ? a64(nb + 512 + t) : 0;
          armstep[go] = tq;
        }
        // prefetch next-step B-slice + rm for this group
        {
          int tsn = (ts + 1 < Tn) ? ts + 1 : Tn - 1;
#pragma unroll
          for (int r = 0; r < 4; r++) {
            int s = quad * 4 + r;
            const ushort* ebp = eb + ((size_t)((pp * 2 + g) * 16 + s) * Tn + tsn) * Hn + gcb;
            bq0[g][r] = ebp[n0 * 16 + l15];
            bq1[g][r] = ebp[n1 * 16 + l15];
          }
          if (hh == 0 && t < 16) rmpre[g] = rm[(size_t)((pp * 2 + g) * 16 + t) * Tn + tsn];
        }
      }
    }
  }

  // ---- finale (hh==0): per group, poll partner's final msg and reduce ----
  if (hh == 0) {
#pragma unroll
    for (int g = 0; g < 2; g++) {
      const int teg = g == 0 ? te0 : te1;
      const int pf = (teg - 1) & 1;
      u64* inb = mb + (size_t)(((pp * 2 + 1) * 2 + g) * 2 + pf) * 520;
      u64 pv = a64(inb + t);
      while (pv == POISON) pv = a64(inb + t);
      if (t < 8) {
        u64 pv2 = a64(inb + 512 + t);
        while (pv2 == POISON) pv2 = a64(inb + 512 + t);
        mpS[g][2 * t] = __uint_as_float((uint)pv2);
        mpS[g][2 * t + 1] = __uint_as_float((uint)(pv2 >> 32));
      }
      u64 ov = Aq[g][0][t];
      float po = 0.f, pe = 0.f;
#pragma unroll
      for (int j = 0; j < 8; j++) {
        po += fp8val((uint)(ov >> (8 * j)) & 0xffu);
        pe += fp8val((uint)(pv >> (8 * j)) & 0xffu);
      }
      po += __shfl_xor(po, 16, 64); po += __shfl_xor(po, 32, 64);
      pe += __shfl_xor(pe, 16, 64); pe += __shfl_xor(pe, 32, 64);
      if (lane < 16) { sred0[w][lane] = po; sred1[w][lane] = pe; }
      __syncthreads();
      if (t < 16) {
        float So = 0.f, Sp = 0.f;
#pragma unroll
        for (int ww = 0; ww < 8; ww++) { So += sred0[ww][t]; Sp += sred1[ww][t]; }
        outp[(pp * 2 + g) * 16 + t] = CaccS[g][t] + logf(moS[g][t] * So + mpS[g][t] * Sp);
      }
      __syncthreads();
    }
  }
}

extern "C" void kernel_launch(void* const* d_in, const int* in_sizes, int n_in,
                              void* d_out, int out_size, void* d_ws, size_t ws_size,
                              hipStream_t stream) {
  const float* seq = (const float*)d_in[0];
  const int* lens = (const int*)d_in[1];
  const float* px = (const float*)d_in[2];
  const float* py = (const float*)d_in[3];
  char* ws = (char*)d_ws;
  ushort* emitb = (ushort*)(ws + 0x0000000);
  float* rm     = (float*)(ws + 0x2000000);
  float* wmat   = (float*)(ws + 0x2020000);
  float* bias   = (float*)(ws + 0x2060000);
  float* cs     = (float*)(ws + 0x2061000);
  float* rcsg   = (float*)(ws + 0x2062000);
  u64* pq       = (u64*)(ws + 0x2070000);
  u64* mb       = (u64*)(ws + 0x20B0000);
  float* outp   = (float*)d_out;

  hipLaunchKernelGGL(k_prep, dim3(512), dim3(128), 0, stream, py, wmat, bias);
  hipLaunchKernelGGL(k_cs, dim3(1), dim3(512), 0, stream, px, cs, rcsg);
  hipLaunchKernelGGL(k_pq, dim3(32), dim3(256), 0, stream, px, cs, pq);
  hipLaunchKernelGGL(k_emit, dim3(8, 512), dim3(256), 0, stream, seq, wmat, bias, emitb);
  hipLaunchKernelGGL(k_rowmax, dim3(NT), dim3(64), 0, stream, emitb, rm);
  hipLaunchKernelGGL(k_bexp, dim3(NT), dim3(256), 0, stream, emitb, rm);
  hipLaunchKernelGGL(k_zero, dim3(33), dim3(256), 0, stream, mb);
  hipLaunchKernelGGL(k_rec3, dim3(4), dim3(512), 0, stream, emitb, rm, pq, px, rcsg, lens, mb, outp);
}